// Round 1
// 1083.176 us; speedup vs baseline: 1.0678x; 1.0678x over previous
//
#include <hip/hip_runtime.h>

typedef __attribute__((ext_vector_type(8))) short short8;
typedef __attribute__((ext_vector_type(4))) float floatx4;

#define M_TOT 131072   // B*S = 64*2048
#define SEQ   2048
#define NB    8        // fallback n-tiles (1024/128)

__device__ __forceinline__ unsigned bf16rne(float x) {
  unsigned u = __float_as_uint(x);
  return (u + 0x7FFFu + ((u >> 16) & 1u)) >> 16;
}

#define GLOAD_LDS16(g, l) __builtin_amdgcn_global_load_lds( \
    (const __attribute__((address_space(1))) unsigned int*)(g), \
    (__attribute__((address_space(3))) unsigned int*)(l), 16, 0, 0)

// ---------------------------------------------------------------------------
// Convert enc fp32 -> bf16 (RNE). 134217728 elems, 8/thread.
// ---------------------------------------------------------------------------
__global__ __launch_bounds__(256) void convert_enc_kernel(
    const float* __restrict__ in, unsigned int* __restrict__ out)
{
  size_t i = ((size_t)blockIdx.x * 256 + threadIdx.x) * 8;
  float4 a = *(const float4*)(in + i);
  float4 b = *(const float4*)(in + i + 4);
  uint4 o;
  o.x = bf16rne(a.x) | (bf16rne(a.y) << 16);
  o.y = bf16rne(a.z) | (bf16rne(a.w) << 16);
  o.z = bf16rne(b.x) | (bf16rne(b.y) << 16);
  o.w = bf16rne(b.z) | (bf16rne(b.w) << 16);
  *(uint4*)(out + i / 2) = o;
}

// ---------------------------------------------------------------------------
// Convert W1e (first 1024 cols of W1's 2048-wide rows) fp32 -> bf16.
// ---------------------------------------------------------------------------
__global__ __launch_bounds__(128) void convert_w1e_kernel(
    const float* __restrict__ W1, unsigned int* __restrict__ out)
{
  int d = blockIdx.x;
  int k = threadIdx.x * 8;
  const float* p = W1 + (size_t)d * 2048 + k;
  float4 a = *(const float4*)p;
  float4 b = *(const float4*)(p + 4);
  uint4 o;
  o.x = bf16rne(a.x) | (bf16rne(a.y) << 16);
  o.y = bf16rne(a.z) | (bf16rne(a.w) << 16);
  o.z = bf16rne(b.x) | (bf16rne(b.y) << 16);
  o.w = bf16rne(b.z) | (bf16rne(b.w) << 16);
  *(uint4*)(out + ((size_t)d * 1024 + k) / 2) = o;
}

// ---------------------------------------------------------------------------
// Kernel 1: hvec[b,d] = b1[d] + sum_m hid[b,m] * W1[d, 1024+m]
// ---------------------------------------------------------------------------
__global__ __launch_bounds__(256) void hvec_kernel(
    const float* __restrict__ hid, const float* __restrict__ W1,
    const float* __restrict__ b1, float* __restrict__ hvec)
{
  int b = blockIdx.x, g = blockIdx.y;
  int w = threadIdx.x >> 6, lane = threadIdx.x & 63;
  const float* hrow = hid + b * 1024;
  for (int i = 0; i < 16; ++i) {
    int d = g * 64 + w * 16 + i;
    const float* wrow = W1 + (size_t)d * 2048 + 1024;
    float sum = 0.f;
#pragma unroll
    for (int c = 0; c < 4; ++c) {
      int m = c * 256 + lane * 4;
      float4 wv = *(const float4*)(wrow + m);
      float4 hv = *(const float4*)(hrow + m);
      sum += wv.x * hv.x + wv.y * hv.y + wv.z * hv.z + wv.w * hv.w;
    }
#pragma unroll
    for (int msk = 1; msk < 64; msk <<= 1) sum += __shfl_xor(sum, msk);
    if (lane == 0) hvec[b * 1024 + d] = sum + b1[d];
  }
}

// ---------------------------------------------------------------------------
// Kernel 2 (primary): 256x256 tile, BK=32, 4-slot LDS ring, counted vmcnt,
// raw s_barrier (1/tile), staging interleaved into the two MFMA phases,
// setprio around MFMA clusters. Epilogue: tanh + W2-dot -> epart (4 planes).
//
// Pipeline invariant: at top of iter t, outstanding gloads = tile t (4 instrs,
// issued iter t-2) + tile t+1 (4, issued iter t-1). vmcnt(4) => tile t landed
// (newest 4 = t+1's). Each wave's vmcnt precedes the barrier, so the barrier
// publishes ALL waves' tile-t chunks. Ring slot (t+2)&3 was last READ at
// iter t-2 (two barriers ago) => no write/read overlap.
// LDS [256][32] bf16 (64B rows): frag ds_read_b128 bank-quad =
// (lrow&1)*4+kq -> 8 lanes/quad = b128 minimum, conflict-free, no swizzle.
// ---------------------------------------------------------------------------
__global__ __launch_bounds__(512, 2) void gemm256_kernel(
    const unsigned short* __restrict__ A, const unsigned short* __restrict__ B,
    const float* __restrict__ W2, const float* __restrict__ hvec,
    float* __restrict__ epart)
{
  __shared__ __align__(16) unsigned short lds[4][2][8192];   // 128 KiB

  const int tid = threadIdx.x;
  const int lid = blockIdx.x;            // 0..2047
  const int xcd = lid & 7, q = lid >> 3; // XCD-contiguous m-ranges, nb fastest
  const int mb = xcd * 64 + (q >> 2);    // 0..511
  const int nb = q & 3;                  // 0..3
  const int r0 = mb * 256, n0 = nb * 256;
  const int bidx = r0 >> 11;             // batch (BM=256 divides S=2048)
  const int wid = tid >> 6, lane = tid & 63;
  const int wm = wid >> 2, wn = wid & 3; // 2M x 4N waves, per-wave 128x64
  const int lrow = lane & 15, kq = lane >> 4;

  // staging maps: dest chunk c = tid + j*512  ->  (row, k-chunk) = (c>>2, c&3)
  int offA[2], offB[2], dst[2];
#pragma unroll
  for (int j = 0; j < 2; ++j) {
    int c = tid + j * 512;
    int r = c >> 2, s = c & 3;
    offA[j] = (r0 + r) * 1024 + s * 8;   // elements (+k0 per tile)
    offB[j] = (n0 + r) * 1024 + s * 8;
    dst[j] = (wid * 64 + j * 512) * 8;   // wave-uniform LDS chunk base (shorts)
  }

  floatx4 acc[8][4];
#pragma unroll
  for (int i = 0; i < 8; ++i)
#pragma unroll
    for (int j = 0; j < 4; ++j)
      acc[i][j] = (floatx4){0.f, 0.f, 0.f, 0.f};

#define STAGE_J(T, J) do { \
    GLOAD_LDS16(A + (size_t)offA[J] + (T) * 32, &lds[(T) & 3][0][dst[J]]); \
    GLOAD_LDS16(B + (size_t)offB[J] + (T) * 32, &lds[(T) & 3][1][dst[J]]); \
  } while (0)

  // prologue: tiles 0 and 1 in flight (8 instrs)
  STAGE_J(0, 0); STAGE_J(0, 1);
  STAGE_J(1, 0); STAGE_J(1, 1);

  const int aB = wm * 4096 + lrow * 32 + kq * 8;
  const int bB = wn * 2048 + lrow * 32 + kq * 8;

  for (int tt = 0; tt < 8; ++tt) {
#pragma unroll
    for (int u = 0; u < 4; ++u) {
      const int t = tt * 4 + u;
      const unsigned short* Ah = lds[u][0];        // (tt*4+u)&3 == u
      const unsigned short* Bh = lds[u][1];

      if (t >= 30) { asm volatile("s_waitcnt vmcnt(0)" ::: "memory"); }
      else         { asm volatile("s_waitcnt vmcnt(4)" ::: "memory"); }
      __builtin_amdgcn_s_barrier();

      short8 af[8];
#pragma unroll
      for (int mt = 0; mt < 8; ++mt) af[mt] = *(const short8*)&Ah[aB + mt * 512];
      short8 bf0 = *(const short8*)&Bh[bB];
      short8 bf1 = *(const short8*)&Bh[bB + 512];
      if (t < 30) STAGE_J(t + 2, 0);               // interleave: issue-early
      __builtin_amdgcn_s_setprio(1);
#pragma unroll
      for (int mt = 0; mt < 8; ++mt) {
        acc[mt][0] = __builtin_amdgcn_mfma_f32_16x16x32_bf16(af[mt], bf0, acc[mt][0], 0, 0, 0);
        acc[mt][1] = __builtin_amdgcn_mfma_f32_16x16x32_bf16(af[mt], bf1, acc[mt][1], 0, 0, 0);
      }
      __builtin_amdgcn_s_setprio(0);
      short8 bf2 = *(const short8*)&Bh[bB + 1024];
      short8 bf3 = *(const short8*)&Bh[bB + 1536];
      if (t < 30) STAGE_J(t + 2, 1);
      __builtin_amdgcn_s_setprio(1);
#pragma unroll
      for (int mt = 0; mt < 8; ++mt) {
        acc[mt][2] = __builtin_amdgcn_mfma_f32_16x16x32_bf16(af[mt], bf2, acc[mt][2], 0, 0, 0);
        acc[mt][3] = __builtin_amdgcn_mfma_f32_16x16x32_bf16(af[mt], bf3, acc[mt][3], 0, 0, 0);
      }
      __builtin_amdgcn_s_setprio(0);
    }
  }
#undef STAGE_J

  // epilogue: e-partials. Reuse LDS slot 0 (all slot-0 reads two barriers old).
  __syncthreads();
  float* ep = (float*)&lds[0][0][0];   // [4 wn][256 m]
  float hv[4], w2v[4];
#pragma unroll
  for (int nt = 0; nt < 4; ++nt) {
    int n = n0 + wn * 64 + nt * 16 + lrow;
    hv[nt]  = hvec[bidx * 1024 + n];
    w2v[nt] = W2[n];
  }
#pragma unroll
  for (int mt = 0; mt < 8; ++mt) {
#pragma unroll
    for (int r = 0; r < 4; ++r) {
      float sum = 0.f;
#pragma unroll
      for (int nt = 0; nt < 4; ++nt) {
        float pre = acc[mt][nt][r] + hv[nt];
        float ex = __expf(2.f * pre);
        sum += (1.f - 2.f / (ex + 1.f)) * w2v[nt];
      }
      sum += __shfl_xor(sum, 1);
      sum += __shfl_xor(sum, 2);
      sum += __shfl_xor(sum, 4);
      sum += __shfl_xor(sum, 8);
      if (lrow == 0) ep[wn * 256 + wm * 128 + mt * 16 + kq * 4 + r] = sum;
    }
  }
  __syncthreads();
  if (tid < 256) {
    float s = ep[tid] + ep[256 + tid] + ep[512 + tid] + ep[768 + tid];
    epart[(size_t)nb * M_TOT + r0 + tid] = s;
  }
}

// ---------------------------------------------------------------------------
// Kernel 2 (fallback, no-ws path): fused GEMM with in-loop convert (128-tile).
// ---------------------------------------------------------------------------
__global__ __launch_bounds__(256) void fused_gemm_kernel(
    const float* __restrict__ enc, const float* __restrict__ W1,
    const float* __restrict__ W2, const float* __restrict__ hvec,
    float* __restrict__ epart)
{
  __shared__ __align__(16) unsigned short Ah[128 * 32];
  __shared__ __align__(16) unsigned short Bh[128 * 32];
  __shared__ float ep[2][128];

  const int tid = threadIdx.x;
  const int nb = blockIdx.x, mb = blockIdx.y;
  const int r0 = mb * 128, n0 = nb * 128;
  const int bidx = r0 >> 11;
  const int w = tid >> 6, lane = tid & 63;
  const int wm = w >> 1, wn = w & 1;
  const int lrow = lane & 15, kq = lane >> 4;

  floatx4 acc[4][4];
#pragma unroll
  for (int i = 0; i < 4; ++i)
#pragma unroll
    for (int j = 0; j < 4; ++j)
      acc[i][j] = (floatx4){0.f, 0.f, 0.f, 0.f};

  const int srow = tid >> 3;
  const int scol = (tid & 7) * 4;
  const float* aptr = enc + (size_t)(r0 + srow) * 1024 + scol;
  const float* bptr = W1  + (size_t)(n0 + srow) * 2048 + scol;

  for (int k0 = 0; k0 < 1024; k0 += 32) {
    float4 av[4], bv[4];
#pragma unroll
    for (int j = 0; j < 4; ++j) {
      av[j] = *(const float4*)(aptr + (size_t)(j * 32) * 1024 + k0);
      bv[j] = *(const float4*)(bptr + (size_t)(j * 32) * 2048 + k0);
    }
    __syncthreads();
#pragma unroll
    for (int j = 0; j < 4; ++j) {
      unsigned ax = __float_as_uint(av[j].x), ay = __float_as_uint(av[j].y);
      unsigned az = __float_as_uint(av[j].z), aw = __float_as_uint(av[j].w);
      unsigned a01 = __builtin_amdgcn_perm(ay, ax, 0x07060302u);
      unsigned a23 = __builtin_amdgcn_perm(aw, az, 0x07060302u);
      *(uint2*)&Ah[(tid + j * 256) * 4] = make_uint2(a01, a23);
      unsigned bx = __float_as_uint(bv[j].x), by = __float_as_uint(bv[j].y);
      unsigned bz = __float_as_uint(bv[j].z), bw = __float_as_uint(bv[j].w);
      unsigned b01 = __builtin_amdgcn_perm(by, bx, 0x07060302u);
      unsigned b23 = __builtin_amdgcn_perm(bw, bz, 0x07060302u);
      *(uint2*)&Bh[(tid + j * 256) * 4] = make_uint2(b01, b23);
    }
    __syncthreads();

    short8 af[4], bfm[4];
#pragma unroll
    for (int t4 = 0; t4 < 4; ++t4) {
      af[t4]  = *(const short8*)&Ah[(wm * 64 + t4 * 16 + lrow) * 32 + kq * 8];
      bfm[t4] = *(const short8*)&Bh[(wn * 64 + t4 * 16 + lrow) * 32 + kq * 8];
    }
#pragma unroll
    for (int mt = 0; mt < 4; ++mt)
#pragma unroll
      for (int nt = 0; nt < 4; ++nt)
        acc[mt][nt] = __builtin_amdgcn_mfma_f32_16x16x32_bf16(
            af[mt], bfm[nt], acc[mt][nt], 0, 0, 0);
  }

  float hv[4], w2v[4];
#pragma unroll
  for (int nt = 0; nt < 4; ++nt) {
    int n = n0 + wn * 64 + nt * 16 + lrow;
    hv[nt]  = hvec[bidx * 1024 + n];
    w2v[nt] = W2[n];
  }
#pragma unroll
  for (int mt = 0; mt < 4; ++mt) {
#pragma unroll
    for (int r = 0; r < 4; ++r) {
      float sum = 0.f;
#pragma unroll
      for (int nt = 0; nt < 4; ++nt) {
        float pre = acc[mt][nt][r] + hv[nt];
        float ex = __expf(2.f * pre);
        sum += (1.f - 2.f / (ex + 1.f)) * w2v[nt];
      }
      sum += __shfl_xor(sum, 1);
      sum += __shfl_xor(sum, 2);
      sum += __shfl_xor(sum, 4);
      sum += __shfl_xor(sum, 8);
      if (lrow == 0) ep[wn][wm * 64 + mt * 16 + kq * 4 + r] = sum;
    }
  }
  __syncthreads();
  if (tid < 128)
    epart[(size_t)nb * M_TOT + r0 + tid] = ep[0][tid] + ep[1][tid];
}

// ---------------------------------------------------------------------------
// Kernel 3: softmax over S per batch. NP = number of epart planes.
// ---------------------------------------------------------------------------
template<int NP>
__global__ __launch_bounds__(256) void softmax_kernel(
    const float* __restrict__ epart, float* __restrict__ alpha)
{
  int b = blockIdx.x, t = threadIdx.x;
  __shared__ float redmax[4], redsum[4];
  float ev[8];
  float lmax = -1e30f;
#pragma unroll
  for (int j = 0; j < 8; ++j) {
    int s = t + j * 256;
    float sum = 0.f;
#pragma unroll
    for (int p = 0; p < NP; ++p) sum += epart[(size_t)p * M_TOT + b * SEQ + s];
    ev[j] = sum;
    lmax = fmaxf(lmax, sum);
  }
#pragma unroll
  for (int msk = 1; msk < 64; msk <<= 1) lmax = fmaxf(lmax, __shfl_xor(lmax, msk));
  if ((t & 63) == 0) redmax[t >> 6] = lmax;
  __syncthreads();
  float bmax = fmaxf(fmaxf(redmax[0], redmax[1]), fmaxf(redmax[2], redmax[3]));
  float lsum = 0.f;
#pragma unroll
  for (int j = 0; j < 8; ++j) { ev[j] = __expf(ev[j] - bmax); lsum += ev[j]; }
#pragma unroll
  for (int msk = 1; msk < 64; msk <<= 1) lsum += __shfl_xor(lsum, msk);
  if ((t & 63) == 0) redsum[t >> 6] = lsum;
  __syncthreads();
  float inv = 1.f / (redsum[0] + redsum[1] + redsum[2] + redsum[3]);
#pragma unroll
  for (int j = 0; j < 8; ++j) alpha[b * SEQ + t + j * 256] = ev[j] * inv;
}

// ---------------------------------------------------------------------------
// Kernel 4 (primary): context, atomic-free. grid (64, 8), block 256.
// ---------------------------------------------------------------------------
__global__ __launch_bounds__(256) void context_bf16_kernel(
    const unsigned int* __restrict__ encB, const float* __restrict__ alpha,
    float* __restrict__ out)
{
  __shared__ float red[8][128];
  int b = blockIdx.x, kc = blockIdx.y, t = threadIdx.x;
  int kl = (t & 31) * 4;
  int strip = t >> 5;
  const unsigned int* ep = encB +
      (((size_t)b * SEQ + strip * 256) * 1024 + kc * 128 + kl) / 2;
  const float* ap = alpha + b * SEQ + strip * 256;
  float a0 = 0.f, a1 = 0.f, a2 = 0.f, a3 = 0.f;
#pragma unroll 4
  for (int s = 0; s < 256; ++s) {
    float a = ap[s];
    uint2 v = *(const uint2*)(ep + (size_t)s * 512);
    a0 += a * __uint_as_float(v.x << 16);
    a1 += a * __uint_as_float(v.x & 0xFFFF0000u);
    a2 += a * __uint_as_float(v.y << 16);
    a3 += a * __uint_as_float(v.y & 0xFFFF0000u);
  }
  red[strip][kl + 0] = a0;
  red[strip][kl + 1] = a1;
  red[strip][kl + 2] = a2;
  red[strip][kl + 3] = a3;
  __syncthreads();
  if (t < 128) {
    float s = 0.f;
#pragma unroll
    for (int j = 0; j < 8; ++j) s += red[j][t];
    out[b * 1024 + kc * 128 + t] = s;
  }
}

// ---------------------------------------------------------------------------
// Kernel 4 (fallback): fp32 context with atomics.
// ---------------------------------------------------------------------------
__global__ __launch_bounds__(256) void context_kernel(
    const float* __restrict__ enc, const float* __restrict__ alpha,
    float* __restrict__ out)
{
  int b = blockIdx.y, sq = blockIdx.z, t = threadIdx.x;
  int k4 = t * 4;
  const float* ep = enc + ((size_t)b * SEQ + sq * 128) * 1024 + k4;
  const float* ap = alpha + b * SEQ + sq * 128;
  float ax = 0.f, ay = 0.f, az = 0.f, aw = 0.f;
#pragma unroll 4
  for (int s = 0; s < 128; ++s) {
    float a = ap[s];
    float4 v = *(const float4*)(ep + (size_t)s * 1024);
    ax += a * v.x; ay += a * v.y; az += a * v.z; aw += a * v.w;
  }
  float* o = out + b * 1024 + k4;
  atomicAdd(o + 0, ax);
  atomicAdd(o + 1, ay);
  atomicAdd(o + 2, az);
  atomicAdd(o + 3, aw);
}

// ---------------------------------------------------------------------------
extern "C" void kernel_launch(void* const* d_in, const int* in_sizes, int n_in,
                              void* d_out, int out_size, void* d_ws, size_t ws_size,
                              hipStream_t stream) {
  const float* hid = (const float*)d_in[0];
  const float* enc = (const float*)d_in[1];
  const float* W1  = (const float*)d_in[2];
  const float* b1  = (const float*)d_in[3];
  const float* W2  = (const float*)d_in[4];
  float* out = (float*)d_out;

  float* epart = (float*)d_ws;                       // NB * M_TOT (8 planes max)
  float* alpha = epart + (size_t)NB * M_TOT;         // M_TOT
  float* hvec  = alpha + M_TOT;                      // 64*1024
  size_t small_bytes = ((size_t)NB * M_TOT + M_TOT + 64 * 1024) * 4;
  size_t encB_off = ((small_bytes + 255) / 256) * 256;
  size_t need = encB_off + (size_t)M_TOT * 1024 * 2 + (size_t)1024 * 1024 * 2;

  hvec_kernel<<<dim3(64, 16), 256, 0, stream>>>(hid, W1, b1, hvec);

  if (ws_size >= need) {
    unsigned short* encB = (unsigned short*)((char*)d_ws + encB_off);
    unsigned short* W1eB = encB + (size_t)M_TOT * 1024;
    convert_enc_kernel<<<65536, 256, 0, stream>>>(enc, (unsigned int*)encB);
    convert_w1e_kernel<<<1024, 128, 0, stream>>>(W1, (unsigned int*)W1eB);
    gemm256_kernel<<<2048, 512, 0, stream>>>(encB, W1eB, W2, hvec, epart);
    softmax_kernel<4><<<64, 256, 0, stream>>>(epart, alpha);
    context_bf16_kernel<<<dim3(64, 8), 256, 0, stream>>>((unsigned int*)encB, alpha, out);
  } else {
    hipMemsetAsync(d_out, 0, (size_t)out_size * sizeof(float), stream);
    fused_gemm_kernel<<<dim3(NB, 1024), 256, 0, stream>>>(enc, W1, W2, hvec, epart);
    softmax_kernel<8><<<64, 256, 0, stream>>>(epart, alpha);
    context_kernel<<<dim3(1, 64, 16), 256, 0, stream>>>(enc, alpha, out);
  }
}